// Round 7
// baseline (225.943 us; speedup 1.0000x reference)
//
#include <hip/hip_runtime.h>

// Haar forward: input (B=8, C=64, H=512, W=512) fp32 NCHW
// output (B, 4*C, 256, 256), subband-major.
// Per 2x2 block {a,b,c,d}: LL=.25(a+b+c+d), k1=.25(a-b+c-d), k2=.25(a+b-c-d), k3=.25(a-b-c+d)
//
// R7 = R4 access pattern (nt float4 loads AND stores — proven best, 192 us)
// + persistent grid-stride: 2048 blocks (32 waves/CU), 16 items/thread,
// unroll 2 so the compiler pipelines next-iteration loads above this
// iteration's stores (__restrict__ makes that legal).

constexpr int B  = 8;
constexpr int C  = 64;
constexpr int H  = 512;
constexpr int W  = 512;
constexpr int HO = H / 2;   // 256
constexpr int WO = W / 2;   // 256
constexpr int W4 = WO / 4;  // 64 float4-chunks per output row
constexpr int TOTAL = B * C * HO * W4;   // 8,388,608

typedef float f32x4 __attribute__((ext_vector_type(4)));

__global__ __launch_bounds__(256) void haar_fwd(const float* __restrict__ x,
                                                float* __restrict__ y) {
    const int stride = gridDim.x * blockDim.x;   // 524288
    const size_t plane = (size_t)HO * WO;

    #pragma unroll 2
    for (int idx = blockIdx.x * blockDim.x + threadIdx.x; idx < TOTAL; idx += stride) {
        const int j4 = idx & (W4 - 1);          // 0..63
        const int i  = (idx >> 6) & (HO - 1);   // 0..255
        const int m  = idx >> 14;               // image = b*C + c (0..511)

        const float* r0 = x + ((size_t)m * H + 2 * (size_t)i) * W + 8 * (size_t)j4;
        const float* r1 = r0 + W;
        const f32x4 r0a = __builtin_nontemporal_load(reinterpret_cast<const f32x4*>(r0));
        const f32x4 r0b = __builtin_nontemporal_load(reinterpret_cast<const f32x4*>(r0 + 4));
        const f32x4 r1a = __builtin_nontemporal_load(reinterpret_cast<const f32x4*>(r1));
        const f32x4 r1b = __builtin_nontemporal_load(reinterpret_cast<const f32x4*>(r1 + 4));

        const float a0 = r0a.x, b0 = r0a.y, a1 = r0a.z, b1 = r0a.w;
        const float a2 = r0b.x, b2 = r0b.y, a3 = r0b.z, b3 = r0b.w;
        const float c0 = r1a.x, d0 = r1a.y, c1 = r1a.z, d1 = r1a.w;
        const float c2 = r1b.x, d2 = r1b.y, c3 = r1b.z, d3 = r1b.w;

        f32x4 ll, k1, k2, k3;
        ll.x = 0.25f * (a0 + b0 + c0 + d0);
        ll.y = 0.25f * (a1 + b1 + c1 + d1);
        ll.z = 0.25f * (a2 + b2 + c2 + d2);
        ll.w = 0.25f * (a3 + b3 + c3 + d3);

        k1.x = 0.25f * (a0 - b0 + c0 - d0);
        k1.y = 0.25f * (a1 - b1 + c1 - d1);
        k1.z = 0.25f * (a2 - b2 + c2 - d2);
        k1.w = 0.25f * (a3 - b3 + c3 - d3);

        k2.x = 0.25f * (a0 + b0 - c0 - d0);
        k2.y = 0.25f * (a1 + b1 - c1 - d1);
        k2.z = 0.25f * (a2 + b2 - c2 - d2);
        k2.w = 0.25f * (a3 + b3 - c3 - d3);

        k3.x = 0.25f * (a0 - b0 - c0 + d0);
        k3.y = 0.25f * (a1 - b1 - c1 + d1);
        k3.z = 0.25f * (a2 - b2 - c2 + d2);
        k3.w = 0.25f * (a3 - b3 - c3 + d3);

        const size_t rowoff = (size_t)i * WO + 4 * (size_t)j4;
        float* yb = y + ((size_t)(m >> 6) * 4 * C + (m & (C - 1))) * plane + rowoff;

        __builtin_nontemporal_store(ll, reinterpret_cast<f32x4*>(yb));
        __builtin_nontemporal_store(k1, reinterpret_cast<f32x4*>(yb + (size_t)C * plane));
        __builtin_nontemporal_store(k2, reinterpret_cast<f32x4*>(yb + (size_t)2 * C * plane));
        __builtin_nontemporal_store(k3, reinterpret_cast<f32x4*>(yb + (size_t)3 * C * plane));
    }
}

extern "C" void kernel_launch(void* const* d_in, const int* in_sizes, int n_in,
                              void* d_out, int out_size, void* d_ws, size_t ws_size,
                              hipStream_t stream) {
    const float* x = (const float*)d_in[0];
    float* y = (float*)d_out;

    const int threads = 256;
    const int blocks = 2048;   // 32 waves/CU persistent; 16 items/thread
    haar_fwd<<<blocks, threads, 0, stream>>>(x, y);
}

// Round 8
// 201.518 us; speedup vs baseline: 1.1212x; 1.1212x over previous
//
#include <hip/hip_runtime.h>

// Haar forward: input (B=8, C=64, H=512, W=512) fp32 NCHW
// output (B, 4*C, 256, 256), subband-major.
// Per 2x2 block {a,b,c,d}: LL=.25(a+b+c+d), k1=.25(a-b+c-d), k2=.25(a+b-c-d), k3=.25(a-b-c+d)
//
// R8 = R4 structure, completing the nt-hint 2x2 A/B matrix:
//   {reg,reg}=211.5  {reg-ld,nt-st}=219.9  {nt,nt}=192.2  {nt-ld,reg-st}=THIS
// nt loads: keep zero-reuse read stream out of L2/L3 (proven +28 us).
// regular stores: let write-back L2 absorb the 4 plane streams and emit
// coarser writeback bursts (R1 vs R6 suggests nt stores cost ~8 us).

constexpr int B  = 8;
constexpr int C  = 64;
constexpr int H  = 512;
constexpr int W  = 512;
constexpr int HO = H / 2;   // 256
constexpr int WO = W / 2;   // 256
constexpr int W4 = WO / 4;  // 64 float4-chunks per output row

typedef float f32x4 __attribute__((ext_vector_type(4)));

__global__ __launch_bounds__(256) void haar_fwd(const float* __restrict__ x,
                                                float* __restrict__ y) {
    const int total = B * C * HO * W4;
    int idx = blockIdx.x * blockDim.x + threadIdx.x;
    if (idx >= total) return;

    const int j4 = idx & (W4 - 1);          // 0..63
    const int i  = (idx >> 6) & (HO - 1);   // 0..255
    const int m  = idx >> 14;               // image = b*C + c (0..511)

    const float* r0 = x + ((size_t)m * H + 2 * (size_t)i) * W + 8 * (size_t)j4;
    const float* r1 = r0 + W;
    const f32x4 r0a = __builtin_nontemporal_load(reinterpret_cast<const f32x4*>(r0));
    const f32x4 r0b = __builtin_nontemporal_load(reinterpret_cast<const f32x4*>(r0 + 4));
    const f32x4 r1a = __builtin_nontemporal_load(reinterpret_cast<const f32x4*>(r1));
    const f32x4 r1b = __builtin_nontemporal_load(reinterpret_cast<const f32x4*>(r1 + 4));

    // Pixel p: a=row0[2p], b=row0[2p+1], c=row1[2p], d=row1[2p+1]
    const float a0 = r0a.x, b0 = r0a.y, a1 = r0a.z, b1 = r0a.w;
    const float a2 = r0b.x, b2 = r0b.y, a3 = r0b.z, b3 = r0b.w;
    const float c0 = r1a.x, d0 = r1a.y, c1 = r1a.z, d1 = r1a.w;
    const float c2 = r1b.x, d2 = r1b.y, c3 = r1b.z, d3 = r1b.w;

    f32x4 ll, k1, k2, k3;
    ll.x = 0.25f * (a0 + b0 + c0 + d0);
    ll.y = 0.25f * (a1 + b1 + c1 + d1);
    ll.z = 0.25f * (a2 + b2 + c2 + d2);
    ll.w = 0.25f * (a3 + b3 + c3 + d3);

    k1.x = 0.25f * (a0 - b0 + c0 - d0);
    k1.y = 0.25f * (a1 - b1 + c1 - d1);
    k1.z = 0.25f * (a2 - b2 + c2 - d2);
    k1.w = 0.25f * (a3 - b3 + c3 - d3);

    k2.x = 0.25f * (a0 + b0 - c0 - d0);
    k2.y = 0.25f * (a1 + b1 - c1 - d1);
    k2.z = 0.25f * (a2 + b2 - c2 - d2);
    k2.w = 0.25f * (a3 + b3 - c3 - d3);

    k3.x = 0.25f * (a0 - b0 - c0 + d0);
    k3.y = 0.25f * (a1 - b1 - c1 + d1);
    k3.z = 0.25f * (a2 - b2 - c2 + d2);
    k3.w = 0.25f * (a3 - b3 - c3 + d3);

    const size_t plane  = (size_t)HO * WO;
    const size_t rowoff = (size_t)i * WO + 4 * (size_t)j4;
    float* yb = y + ((size_t)(m >> 6) * 4 * C + (m & (C - 1))) * plane + rowoff;

    *reinterpret_cast<f32x4*>(yb)                         = ll;
    *reinterpret_cast<f32x4*>(yb + (size_t)C * plane)     = k1;
    *reinterpret_cast<f32x4*>(yb + (size_t)2 * C * plane) = k2;
    *reinterpret_cast<f32x4*>(yb + (size_t)3 * C * plane) = k3;
}

extern "C" void kernel_launch(void* const* d_in, const int* in_sizes, int n_in,
                              void* d_out, int out_size, void* d_ws, size_t ws_size,
                              hipStream_t stream) {
    const float* x = (const float*)d_in[0];
    float* y = (float*)d_out;

    const int total = B * C * HO * W4;   // 8,388,608 threads
    const int threads = 256;
    const int blocks = (total + threads - 1) / threads;   // 32768
    haar_fwd<<<blocks, threads, 0, stream>>>(x, y);
}

// Round 9
// 196.639 us; speedup vs baseline: 1.1490x; 1.0248x over previous
//
#include <hip/hip_runtime.h>

// Haar forward: input (B=8, C=64, H=512, W=512) fp32 NCHW
// output (B, 4*C, 256, 256), subband-major.
// Per 2x2 block {a,b,c,d}: LL=.25(a+b+c+d), k1=.25(a-b+c-d), k2=.25(a+b-c-d), k3=.25(a-b-c+d)
//
// R9 = R4 (nt loads + nt stores, one item/thread — best, 192.2 us) with ONE
// knob: 1024-thread blocks (16 waves). Block now covers 16 consecutive output
// rows of one image: 64 KiB contiguous read span, 16 KiB contiguous write
// per plane -> coarser DRAM page locality, 8192 blocks instead of 32768.
// nt 2x2 matrix measured: {reg,reg}=211.5 {reg,nt}=219.9 {nt,reg}=201.5 {nt,nt}=192.2.

constexpr int B  = 8;
constexpr int C  = 64;
constexpr int H  = 512;
constexpr int W  = 512;
constexpr int HO = H / 2;   // 256
constexpr int WO = W / 2;   // 256
constexpr int W4 = WO / 4;  // 64 float4-chunks per output row

typedef float f32x4 __attribute__((ext_vector_type(4)));

__global__ __launch_bounds__(1024) void haar_fwd(const float* __restrict__ x,
                                                 float* __restrict__ y) {
    const int total = B * C * HO * W4;
    int idx = blockIdx.x * blockDim.x + threadIdx.x;
    if (idx >= total) return;

    const int j4 = idx & (W4 - 1);          // 0..63
    const int i  = (idx >> 6) & (HO - 1);   // 0..255
    const int m  = idx >> 14;               // image = b*C + c (0..511)

    const float* r0 = x + ((size_t)m * H + 2 * (size_t)i) * W + 8 * (size_t)j4;
    const float* r1 = r0 + W;
    const f32x4 r0a = __builtin_nontemporal_load(reinterpret_cast<const f32x4*>(r0));
    const f32x4 r0b = __builtin_nontemporal_load(reinterpret_cast<const f32x4*>(r0 + 4));
    const f32x4 r1a = __builtin_nontemporal_load(reinterpret_cast<const f32x4*>(r1));
    const f32x4 r1b = __builtin_nontemporal_load(reinterpret_cast<const f32x4*>(r1 + 4));

    // Pixel p: a=row0[2p], b=row0[2p+1], c=row1[2p], d=row1[2p+1]
    const float a0 = r0a.x, b0 = r0a.y, a1 = r0a.z, b1 = r0a.w;
    const float a2 = r0b.x, b2 = r0b.y, a3 = r0b.z, b3 = r0b.w;
    const float c0 = r1a.x, d0 = r1a.y, c1 = r1a.z, d1 = r1a.w;
    const float c2 = r1b.x, d2 = r1b.y, c3 = r1b.z, d3 = r1b.w;

    f32x4 ll, k1, k2, k3;
    ll.x = 0.25f * (a0 + b0 + c0 + d0);
    ll.y = 0.25f * (a1 + b1 + c1 + d1);
    ll.z = 0.25f * (a2 + b2 + c2 + d2);
    ll.w = 0.25f * (a3 + b3 + c3 + d3);

    k1.x = 0.25f * (a0 - b0 + c0 - d0);
    k1.y = 0.25f * (a1 - b1 + c1 - d1);
    k1.z = 0.25f * (a2 - b2 + c2 - d2);
    k1.w = 0.25f * (a3 - b3 + c3 - d3);

    k2.x = 0.25f * (a0 + b0 - c0 - d0);
    k2.y = 0.25f * (a1 + b1 - c1 - d1);
    k2.z = 0.25f * (a2 + b2 - c2 - d2);
    k2.w = 0.25f * (a3 + b3 - c3 - d3);

    k3.x = 0.25f * (a0 - b0 - c0 + d0);
    k3.y = 0.25f * (a1 - b1 - c1 + d1);
    k3.z = 0.25f * (a2 - b2 - c2 + d2);
    k3.w = 0.25f * (a3 - b3 - c3 + d3);

    const size_t plane  = (size_t)HO * WO;
    const size_t rowoff = (size_t)i * WO + 4 * (size_t)j4;
    float* yb = y + ((size_t)(m >> 6) * 4 * C + (m & (C - 1))) * plane + rowoff;

    __builtin_nontemporal_store(ll, reinterpret_cast<f32x4*>(yb));
    __builtin_nontemporal_store(k1, reinterpret_cast<f32x4*>(yb + (size_t)C * plane));
    __builtin_nontemporal_store(k2, reinterpret_cast<f32x4*>(yb + (size_t)2 * C * plane));
    __builtin_nontemporal_store(k3, reinterpret_cast<f32x4*>(yb + (size_t)3 * C * plane));
}

extern "C" void kernel_launch(void* const* d_in, const int* in_sizes, int n_in,
                              void* d_out, int out_size, void* d_ws, size_t ws_size,
                              hipStream_t stream) {
    const float* x = (const float*)d_in[0];
    float* y = (float*)d_out;

    const int total = B * C * HO * W4;   // 8,388,608 threads
    const int threads = 1024;
    const int blocks = (total + threads - 1) / threads;   // 8192
    haar_fwd<<<blocks, threads, 0, stream>>>(x, y);
}

// Round 10
// 191.908 us; speedup vs baseline: 1.1774x; 1.0247x over previous
//
#include <hip/hip_runtime.h>

// Haar forward: input (B=8, C=64, H=512, W=512) fp32 NCHW
// output (B, 4*C, 256, 256), subband-major.
// Per 2x2 block {a,b,c,d}: LL=.25(a+b+c+d), k1=.25(a-b+c-d), k2=.25(a+b-c-d), k3=.25(a-b-c+d)
//
// FINAL = R4 winner: one item/thread, 256-thread blocks, nt float4 loads AND
// stores. 192.2 us = 5.59 TB/s effective (89% of measured 6.29 TB/s copy
// ceiling) with 1 read + 4 write streams.
// Search log: scalar->float4 (211), grid-stride float2 (241), nt both (192),
// LDS bounce (213), reg-ld/nt-st (220), grid-stride nt (226), nt-ld/reg-st
// (201.5), 1024-thr blocks (196.6). nt 2x2 matrix: {nt,nt} best; effects
// interact — partial cache bypass thrashes, full bypass wins.

constexpr int B  = 8;
constexpr int C  = 64;
constexpr int H  = 512;
constexpr int W  = 512;
constexpr int HO = H / 2;   // 256
constexpr int WO = W / 2;   // 256
constexpr int W4 = WO / 4;  // 64 float4-chunks per output row

typedef float f32x4 __attribute__((ext_vector_type(4)));

__global__ __launch_bounds__(256) void haar_fwd(const float* __restrict__ x,
                                                float* __restrict__ y) {
    const int total = B * C * HO * W4;
    int idx = blockIdx.x * blockDim.x + threadIdx.x;
    if (idx >= total) return;

    const int j4 = idx & (W4 - 1);          // 0..63
    const int i  = (idx >> 6) & (HO - 1);   // 0..255
    const int m  = idx >> 14;               // image = b*C + c (0..511)

    const float* r0 = x + ((size_t)m * H + 2 * (size_t)i) * W + 8 * (size_t)j4;
    const float* r1 = r0 + W;
    const f32x4 r0a = __builtin_nontemporal_load(reinterpret_cast<const f32x4*>(r0));
    const f32x4 r0b = __builtin_nontemporal_load(reinterpret_cast<const f32x4*>(r0 + 4));
    const f32x4 r1a = __builtin_nontemporal_load(reinterpret_cast<const f32x4*>(r1));
    const f32x4 r1b = __builtin_nontemporal_load(reinterpret_cast<const f32x4*>(r1 + 4));

    // Pixel p: a=row0[2p], b=row0[2p+1], c=row1[2p], d=row1[2p+1]
    const float a0 = r0a.x, b0 = r0a.y, a1 = r0a.z, b1 = r0a.w;
    const float a2 = r0b.x, b2 = r0b.y, a3 = r0b.z, b3 = r0b.w;
    const float c0 = r1a.x, d0 = r1a.y, c1 = r1a.z, d1 = r1a.w;
    const float c2 = r1b.x, d2 = r1b.y, c3 = r1b.z, d3 = r1b.w;

    f32x4 ll, k1, k2, k3;
    ll.x = 0.25f * (a0 + b0 + c0 + d0);
    ll.y = 0.25f * (a1 + b1 + c1 + d1);
    ll.z = 0.25f * (a2 + b2 + c2 + d2);
    ll.w = 0.25f * (a3 + b3 + c3 + d3);

    k1.x = 0.25f * (a0 - b0 + c0 - d0);
    k1.y = 0.25f * (a1 - b1 + c1 - d1);
    k1.z = 0.25f * (a2 - b2 + c2 - d2);
    k1.w = 0.25f * (a3 - b3 + c3 - d3);

    k2.x = 0.25f * (a0 + b0 - c0 - d0);
    k2.y = 0.25f * (a1 + b1 - c1 - d1);
    k2.z = 0.25f * (a2 + b2 - c2 - d2);
    k2.w = 0.25f * (a3 + b3 - c3 - d3);

    k3.x = 0.25f * (a0 - b0 - c0 + d0);
    k3.y = 0.25f * (a1 - b1 - c1 + d1);
    k3.z = 0.25f * (a2 - b2 - c2 + d2);
    k3.w = 0.25f * (a3 - b3 - c3 + d3);

    const size_t plane  = (size_t)HO * WO;
    const size_t rowoff = (size_t)i * WO + 4 * (size_t)j4;
    float* yb = y + ((size_t)(m >> 6) * 4 * C + (m & (C - 1))) * plane + rowoff;

    __builtin_nontemporal_store(ll, reinterpret_cast<f32x4*>(yb));
    __builtin_nontemporal_store(k1, reinterpret_cast<f32x4*>(yb + (size_t)C * plane));
    __builtin_nontemporal_store(k2, reinterpret_cast<f32x4*>(yb + (size_t)2 * C * plane));
    __builtin_nontemporal_store(k3, reinterpret_cast<f32x4*>(yb + (size_t)3 * C * plane));
}

extern "C" void kernel_launch(void* const* d_in, const int* in_sizes, int n_in,
                              void* d_out, int out_size, void* d_ws, size_t ws_size,
                              hipStream_t stream) {
    const float* x = (const float*)d_in[0];
    float* y = (float*)d_out;

    const int total = B * C * HO * W4;   // 8,388,608 threads
    const int threads = 256;
    const int blocks = (total + threads - 1) / threads;   // 32768
    haar_fwd<<<blocks, threads, 0, stream>>>(x, y);
}